// Round 13
// baseline (845.483 us; speedup 1.0000x reference)
//
#include <hip/hip_runtime.h>
#include <math.h>

#define TS 2048

typedef float f32x2 __attribute__((ext_vector_type(2)));
typedef _Float16 f16;
typedef _Float16 f16x2 __attribute__((ext_vector_type(2)));
typedef _Float16 f16x8 __attribute__((ext_vector_type(8)));

// LDS float-index map (13920 f32 = 55.7 KB)
#define XG0_B  5120
#define XG1_B  8192
#define H0H_B  11264
#define H1H_B  12288
#define H1F_B  12800
#define SCRO_B 13824
#define LDSF   13920

#define BAR() do { asm volatile("s_waitcnt lgkmcnt(0)" ::: "memory"); __builtin_amdgcn_s_barrier(); } while(0)
#define FEN() asm volatile("s_waitcnt lgkmcnt(0)" ::: "memory")

union H8 { f16x8 v8; f16x2 v2[4]; };

__device__ __forceinline__ float sigmoidf_(float v){ return __builtin_amdgcn_rcpf(1.0f+__expf(-v)); }
__device__ __forceinline__ float tanhf_(float v){
  v = fminf(15.0f, fmaxf(-15.0f, v));
  const float e = __expf(2.0f*v);
  return (e-1.0f)*__builtin_amdgcn_rcpf(e+1.0f);
}
__device__ __forceinline__ float qadd1(float v){
  return v + __int_as_float(__builtin_amdgcn_update_dpp(0, __float_as_int(v), 0xB1, 0xF, 0xF, true));
}
__device__ __forceinline__ float wsum64(float v){
  v += __int_as_float(__builtin_amdgcn_update_dpp(0, __float_as_int(v), 0x111, 0xF, 0xF, true));
  v += __int_as_float(__builtin_amdgcn_update_dpp(0, __float_as_int(v), 0x112, 0xF, 0xF, true));
  v += __int_as_float(__builtin_amdgcn_update_dpp(0, __float_as_int(v), 0x114, 0xF, 0xF, true));
  v += __int_as_float(__builtin_amdgcn_update_dpp(0, __float_as_int(v), 0x118, 0xF, 0xF, true));
  v += __int_as_float(__builtin_amdgcn_update_dpp(0, __float_as_int(v), 0x142, 0xA, 0xF, true));
  v += __int_as_float(__builtin_amdgcn_update_dpp(0, __float_as_int(v), 0x143, 0xC, 0xF, true));
  return __int_as_float(__builtin_amdgcn_readlane(__float_as_int(v), 63));
}
__device__ __forceinline__ float fdot2_(f16x2 a, f16x2 b, float c){
  return __builtin_amdgcn_fdot2(a, b, c, false);
}

// 6 half-dots via v_pk_fma_f16 (full-rate): 96 pk-fma, 12 f16x2 accumulators
// (2 chains of 8 per dot), combine = pk_add + 2 cvt + add per dot.
__device__ __forceinline__ void dot6pk(const f16* vec, const f16x2* Wp, float* r){
  H8 u[4];
  u[0].v8 = *(const f16x8*)(vec);
  u[1].v8 = *(const f16x8*)(vec+8);
  u[2].v8 = *(const f16x8*)(vec+16);
  u[3].v8 = *(const f16x8*)(vec+24);
  f16x2 acc[12];
  #pragma unroll
  for (int d=0; d<12; d++) acc[d] = (f16x2){(f16)0.f,(f16)0.f};
  #pragma unroll
  for (int m=0;m<16;m++){
    const f16x2 hm = u[m>>2].v2[m&3];
    const int s = m&1;
    acc[0+s]  = __builtin_elementwise_fma(Wp[m],    hm, acc[0+s]);
    acc[2+s]  = __builtin_elementwise_fma(Wp[16+m], hm, acc[2+s]);
    acc[4+s]  = __builtin_elementwise_fma(Wp[32+m], hm, acc[4+s]);
    acc[6+s]  = __builtin_elementwise_fma(Wp[48+m], hm, acc[6+s]);
    acc[8+s]  = __builtin_elementwise_fma(Wp[64+m], hm, acc[8+s]);
    acc[10+s] = __builtin_elementwise_fma(Wp[80+m], hm, acc[10+s]);
  }
  #pragma unroll
  for (int d=0; d<6; d++){
    const f16x2 t = acc[2*d] + acc[2*d+1];   // v_pk_add_f16
    r[d] = (float)t[0] + (float)t[1];
  }
}

// 7 waves = 448 threads (wid&3 = SIMD):
//  w0 = L0 recurrence   w1 = L1 recurrence   (critical chains, setprio 1)
//  w2 = F1: xg1 = W_ih1·h0 + b_ih1   w3 = F0: xg0 = W_ih0·x + b_ih0
//  w4 = x stager   w5 = idle   w6 = attn+pool
// Superblocks of D=8 steps; ONE block barrier per superblock.
__global__ __launch_bounds__(448, 1)
void gru_attn_fused(const float* __restrict__ x,
                    const float* __restrict__ w_ih0, const float* __restrict__ w_hh0,
                    const float* __restrict__ b_ih0, const float* __restrict__ b_hh0,
                    const float* __restrict__ w_ih1, const float* __restrict__ w_hh1,
                    const float* __restrict__ b_ih1, const float* __restrict__ b_hh1,
                    const float* __restrict__ attn_w1, const float* __restrict__ attn_b1,
                    const float* __restrict__ attn_w2, const float* __restrict__ attn_b2,
                    const float* __restrict__ ln_g, const float* __restrict__ ln_b,
                    const float* __restrict__ head_w1, const float* __restrict__ head_b1,
                    const float* __restrict__ head_w2, const float* __restrict__ head_b2,
                    float* __restrict__ out)
{
  __shared__ float lds[LDSF];
  f16*   ldsx = (f16*)lds;
  float* xg0  = lds + XG0_B;
  float* xg1  = lds + XG1_B;
  f16*   h0h  = (f16*)(lds + H0H_B);
  f16*   h1h  = (f16*)(lds + H1H_B);
  float* h1f  = lds + H1F_B;

  const int tid  = threadIdx.x;
  const int wid  = tid >> 6;
  const int lane = tid & 63;
  const int b    = blockIdx.x;
  const float* xb = x + (size_t)b * 64 * TS;

  const int i2     = lane >> 1;
  const int p      = lane & 1;
  const int ownrow = i2 + 32*p;
  const int hoff   = p << 5;

  f16x2 W[96];
  float4 SP[16];
  float bA=0.f,bB=0.f,bC=0.f,w2o=0.f,b2v=0.f;

  if (wid < 4) {
    const float* wsrc = (wid==0)? w_hh0 : (wid==1)? w_hh1 : (wid==2)? w_ih1 : w_ih0;
    for (int r2=0;r2<2;r2++)
      for (int g=0;g<3;g++)
        for (int m=0;m<16;m++){
          const f32x2 v = *(const f32x2*)(wsrc + (size_t)(g*64 + i2 + 32*r2)*64 + hoff + 2*m);
          W[(r2*3+g)*16+m] = (f16x2){(f16)v.x,(f16)v.y};
        }
    for (int q2=0;q2<96;q2++) asm volatile("" : "+v"(W[q2]));
    const float* bsrc = (wid==0)? b_hh0 : (wid==1)? b_hh1 : (wid==2)? b_ih1 : b_ih0;
    bA = bsrc[ownrow]; bB = bsrc[64+ownrow]; bC = bsrc[128+ownrow];
  } else if (wid == 6) {
    for (int r2=0;r2<2;r2++)
      for (int m=0;m<16;m++){
        const f32x2 v = *(const f32x2*)(attn_w1 + (size_t)(i2+32*r2)*64 + hoff + 2*m);
        W[r2*16+m] = (f16x2){(f16)v.x,(f16)v.y};
      }
    for (int q2=0;q2<32;q2++) asm volatile("" : "+v"(W[q2]));
    bA = attn_b1[ownrow]; w2o = attn_w2[ownrow]; b2v = attn_b2[0];
  }

  for (int idx = tid; idx < 1024; idx += 448) ((uint32_t*)h0h)[idx] = 0u;
  for (int idx = tid; idx < 512;  idx += 448) ((uint32_t*)h1h)[idx] = 0u;
  if (wid == 4) {
    const float* src = xb + (size_t)lane*TS;
    #pragma unroll
    for (int kq=0;kq<16;kq++) SP[kq] = *(const float4*)(src + 4*kq);
    #pragma unroll
    for (int kq=0;kq<16;kq++){
      ldsx[(4*kq+0)*80 + lane] = (f16)SP[kq].x;
      ldsx[(4*kq+1)*80 + lane] = (f16)SP[kq].y;
      ldsx[(4*kq+2)*80 + lane] = (f16)SP[kq].z;
      ldsx[(4*kq+3)*80 + lane] = (f16)SP[kq].w;
    }
  }
  __syncthreads();

  if (wid <= 1) __builtin_amdgcn_s_setprio(1);

  float hreg = 0.f;
  float am = -1e30f, aZ = 0.f, aP = 0.f;

  #pragma unroll 1
  for (int k = -1; k <= 258; ++k) {
    if (wid <= 1) {
      const int blk = k - (wid << 1);
      if (0 <= blk && blk < 256) {
        f16*   hring = wid ? h1h : h0h;
        float* xgc   = wid ? xg1 : xg0;
        const int emask = wid ? 1023 : 2047;
        // xg preamble read for step 8*blk (written a full SB ago; barrier-safe)
        const int t0 = blk << 3;
        float xgr = xgc[(t0&15)*192 + ownrow];
        float xgz = xgc[(t0&15)*192 + 64 + ownrow];
        float xgn = xgc[(t0&15)*192 + 128 + ownrow];
        #pragma unroll
        for (int j=0;j<8;j++){
          const int t = t0 + j;
          FEN();                                            // drain h write(t-1) + xg reads
          const f16* hv = hring + (((t-1)<<6) & emask) + hoff;
          float rr[6];
          dot6pk(hv, W, rr);
          const float a00=qadd1(rr[0]), a01=qadd1(rr[1]), a02=qadd1(rr[2]);
          const float a10=qadd1(rr[3]), a11=qadd1(rr[4]), a12=qadd1(rr[5]);
          const float hr = p ? a10 : a00;
          const float hz = p ? a11 : a01;
          const float hn = p ? a12 : a02;
          const float r = sigmoidf_(xgr + hr + bA);
          const float z = sigmoidf_(xgz + hz + bB);
          const float n = tanhf_(xgn + r*(hn + bC));
          hreg = n + z*(hreg - n);
          hring[((t<<6) & emask) + ownrow] = (f16)hreg;
          if (wid) h1f[((t&15)<<6) + ownrow] = hreg;
          if (j < 7) {                                      // prefetch xg(t+1), same SB
            const int xi = ((t+1)&15)*192;
            xgr = xgc[xi + ownrow];
            xgz = xgc[xi + 64 + ownrow];
            xgn = xgc[xi + 128 + ownrow];
          }
        }
      }
    } else if (wid <= 3) {
      const int blk = (wid==2) ? k-1 : k+1;
      if (0 <= blk && blk < 256) {
        float* xgw = (wid==2) ? xg1 : xg0;
        #pragma unroll
        for (int j=0;j<8;j++){
          const int t = (blk<<3) + j;
          const f16* vec;
          if (wid==2) vec = h0h + (((t-1)<<6) & 2047) + hoff;
          else        vec = ldsx + ((t>>6)&1)*5120 + (t&63)*80 + hoff;
          float rr[6];
          dot6pk(vec, W, rr);
          const float a00=qadd1(rr[0]), a01=qadd1(rr[1]), a02=qadd1(rr[2]);
          const float a10=qadd1(rr[3]), a11=qadd1(rr[4]), a12=qadd1(rr[5]);
          const int xi = (t & 15) * 192;
          xgw[xi + ownrow]       = (p ? a10 : a00) + bA;
          xgw[xi + 64 + ownrow]  = (p ? a11 : a01) + bB;
          xgw[xi + 128 + ownrow] = (p ? a12 : a02) + bC;
        }
      }
    } else if (wid == 4) {
      const int kk = k + 1, tile = kk >> 3, ph = kk & 7;
      if (ph == 1 && tile < 31) {
        const float* src = xb + (size_t)lane*TS + (tile+1)*64;
        #pragma unroll
        for (int kq=0;kq<16;kq++) SP[kq] = *(const float4*)(src + 4*kq);
      } else if (ph == 5 && tile < 31) {
        f16* dsth = ldsx + ((tile+1)&1)*5120;
        #pragma unroll
        for (int kq=0;kq<16;kq++){
          dsth[(4*kq+0)*80 + lane] = (f16)SP[kq].x;
          dsth[(4*kq+1)*80 + lane] = (f16)SP[kq].y;
          dsth[(4*kq+2)*80 + lane] = (f16)SP[kq].z;
          dsth[(4*kq+3)*80 + lane] = (f16)SP[kq].w;
        }
      }
    } else if (wid == 6) {
      const int blk = k - 3;
      if (0 <= blk && blk < 256) {
        #pragma unroll
        for (int j=0;j<8;j++){
          const int t = (blk<<3) + j;
          const f16* hv = h1h + ((t&15)<<6) + hoff;
          H8 u[4];
          u[0].v8 = *(const f16x8*)(hv);
          u[1].v8 = *(const f16x8*)(hv+8);
          u[2].v8 = *(const f16x8*)(hv+16);
          u[3].v8 = *(const f16x8*)(hv+24);
          float a0=0.f, a1=0.f;
          #pragma unroll
          for (int m=0;m<16;m++){
            const f16x2 hm = u[m>>2].v2[m&3];
            a0 = fdot2_(W[m],    hm, a0);
            a1 = fdot2_(W[16+m], hm, a1);
          }
          a0 = qadd1(a0); a1 = qadd1(a1);
          const float a  = tanhf_((p ? a1 : a0) + bA);
          const float s  = wsum64(w2o * a) + b2v;
          const float hc = h1f[((t&15)<<6) + lane];
          const float mn = fmaxf(am, s);
          const float sc = __expf(am - mn);
          const float pp = __expf(s - mn);
          aZ = aZ*sc + pp;
          aP = aP*sc + pp*hc;
          am = mn;
        }
      }
    }
    BAR();
  }

  // ---------------- epilogue ----------------
  if (wid == 6) {
    const float pooled = aP / aZ;
    float mu = pooled;
    #pragma unroll
    for (int m=1;m<64;m<<=1) mu += __shfl_xor(mu, m, 64);
    mu *= (1.0f/64.0f);
    const float d = pooled - mu;
    float var = d*d;
    #pragma unroll
    for (int m=1;m<64;m<<=1) var += __shfl_xor(var, m, 64);
    var *= (1.0f/64.0f);
    const float y = d * rsqrtf(var + 1e-5f) * ln_g[lane] + ln_b[lane];
    lds[SCRO_B + lane] = y;
  }
  __syncthreads();
  if (tid < 32) {
    const float* hw = head_w1 + tid*64;
    float acc = head_b1[tid];
    #pragma unroll
    for (int kq=0;kq<16;kq++){
      const float4 w4 = ((const float4*)hw)[kq];
      acc += w4.x*lds[SCRO_B+4*kq+0] + w4.y*lds[SCRO_B+4*kq+1]
           + w4.z*lds[SCRO_B+4*kq+2] + w4.w*lds[SCRO_B+4*kq+3];
    }
    const float u = 0.5f*acc*(1.0f + erff(acc*0.70710678118654752f)); // exact GELU
    lds[SCRO_B + 64 + tid] = u;
  }
  __syncthreads();
  if (tid < 8) {
    const float* hw = head_w2 + tid*32;
    float acc = head_b2[tid];
    #pragma unroll
    for (int kq=0;kq<8;kq++){
      const float4 w4 = ((const float4*)hw)[kq];
      acc += w4.x*lds[SCRO_B+64+4*kq+0] + w4.y*lds[SCRO_B+64+4*kq+1]
           + w4.z*lds[SCRO_B+64+4*kq+2] + w4.w*lds[SCRO_B+64+4*kq+3];
    }
    out[b*8 + tid] = acc;
  }
}

extern "C" void kernel_launch(void* const* d_in, const int* in_sizes, int n_in,
                              void* d_out, int out_size, void* d_ws, size_t ws_size,
                              hipStream_t stream) {
  (void)in_sizes; (void)n_in; (void)d_ws; (void)ws_size; (void)out_size;
  const float* x       = (const float*)d_in[0];
  const float* w_ih0   = (const float*)d_in[1];
  const float* w_hh0   = (const float*)d_in[2];
  const float* b_ih0   = (const float*)d_in[3];
  const float* b_hh0   = (const float*)d_in[4];
  const float* w_ih1   = (const float*)d_in[5];
  const float* w_hh1   = (const float*)d_in[6];
  const float* b_ih1   = (const float*)d_in[7];
  const float* b_hh1   = (const float*)d_in[8];
  const float* attn_w1 = (const float*)d_in[9];
  const float* attn_b1 = (const float*)d_in[10];
  const float* attn_w2 = (const float*)d_in[11];
  const float* attn_b2 = (const float*)d_in[12];
  const float* ln_g    = (const float*)d_in[13];
  const float* ln_b    = (const float*)d_in[14];
  const float* head_w1 = (const float*)d_in[15];
  const float* head_b1 = (const float*)d_in[16];
  const float* head_w2 = (const float*)d_in[17];
  const float* head_b2 = (const float*)d_in[18];
  hipLaunchKernelGGL(gru_attn_fused, dim3(256), dim3(448), 0, stream,
                     x, w_ih0, w_hh0, b_ih0, b_hh0, w_ih1, w_hh1, b_ih1, b_hh1,
                     attn_w1, attn_b1, attn_w2, attn_b2, ln_g, ln_b,
                     head_w1, head_b1, head_w2, head_b2, (float*)d_out);
}

// Round 16
// 793.868 us; speedup vs baseline: 1.0650x; 1.0650x over previous
//
#include <hip/hip_runtime.h>
#include <math.h>

#define TS 2048

typedef float f32x2 __attribute__((ext_vector_type(2)));
typedef _Float16 f16;
typedef _Float16 f16x2 __attribute__((ext_vector_type(2)));
typedef _Float16 f16x8 __attribute__((ext_vector_type(8)));

// LDS float-index map (13920 f32 = 55.7 KB)
#define XG0_B  5120
#define XG1_B  8192
#define H0H_B  11264
#define H1H_B  12288
#define H1F_B  12800
#define SCRO_B 13824
#define LDSF   13920

#define BAR() do { asm volatile("s_waitcnt lgkmcnt(0)" ::: "memory"); __builtin_amdgcn_s_barrier(); } while(0)
#define FEN() asm volatile("s_waitcnt lgkmcnt(0)" ::: "memory")

union H8 { f16x8 v8; f16x2 v2[4]; };

__device__ __forceinline__ float sigmoidf_(float v){ return __builtin_amdgcn_rcpf(1.0f+__expf(-v)); }
__device__ __forceinline__ float tanhf_(float v){
  v = fminf(15.0f, fmaxf(-15.0f, v));
  const float e = __expf(2.0f*v);
  return (e-1.0f)*__builtin_amdgcn_rcpf(e+1.0f);
}
__device__ __forceinline__ float qadd1(float v){
  return v + __int_as_float(__builtin_amdgcn_update_dpp(0, __float_as_int(v), 0xB1, 0xF, 0xF, true));
}
__device__ __forceinline__ float wsum64(float v){
  v += __int_as_float(__builtin_amdgcn_update_dpp(0, __float_as_int(v), 0x111, 0xF, 0xF, true));
  v += __int_as_float(__builtin_amdgcn_update_dpp(0, __float_as_int(v), 0x112, 0xF, 0xF, true));
  v += __int_as_float(__builtin_amdgcn_update_dpp(0, __float_as_int(v), 0x114, 0xF, 0xF, true));
  v += __int_as_float(__builtin_amdgcn_update_dpp(0, __float_as_int(v), 0x118, 0xF, 0xF, true));
  v += __int_as_float(__builtin_amdgcn_update_dpp(0, __float_as_int(v), 0x142, 0xA, 0xF, true));
  v += __int_as_float(__builtin_amdgcn_update_dpp(0, __float_as_int(v), 0x143, 0xC, 0xF, true));
  return __int_as_float(__builtin_amdgcn_readlane(__float_as_int(v), 63));
}
__device__ __forceinline__ float fdot2_(f16x2 a, f16x2 b, float c){
  return __builtin_amdgcn_fdot2(a, b, c, false);
}
// 6 half-dots (rows {i2,i2+32} x 3 gates, 32-f16 half each): 96 fdot2
__device__ __forceinline__ void dot6(const f16* vec, const f16x2* Wp,
                                     float& a00, float& a01, float& a02,
                                     float& a10, float& a11, float& a12){
  H8 u[4];
  u[0].v8 = *(const f16x8*)(vec);
  u[1].v8 = *(const f16x8*)(vec+8);
  u[2].v8 = *(const f16x8*)(vec+16);
  u[3].v8 = *(const f16x8*)(vec+24);
  #pragma unroll
  for (int m=0;m<16;m++){
    const f16x2 hm = u[m>>2].v2[m&3];
    a00 = fdot2_(Wp[m],    hm, a00);
    a01 = fdot2_(Wp[16+m], hm, a01);
    a02 = fdot2_(Wp[32+m], hm, a02);
    a10 = fdot2_(Wp[48+m], hm, a10);
    a11 = fdot2_(Wp[64+m], hm, a11);
    a12 = fdot2_(Wp[80+m], hm, a12);
  }
}

// 7 waves = 448 threads (wid&3 = SIMD):
//  w0 = L0 recurrence   w1 = L1 recurrence   (critical chains, setprio 1)
//  w2 = F1: xg1 = W_ih1·h0 + b_ih1   w3 = F0: xg0 = W_ih0·x + b_ih0
//  w4 = x stager   w5 = idle   w6 = attn+pool
// Superblocks of D=8 steps; ONE block barrier per superblock.
// Delta vs R12 (792us passing): xg(t+1) prefetched before the next step's FEN.
// NOTE: pair-reduce (qadd1) must be applied to EACH accumulator BEFORE the
// p-select — the paired lanes hold partials of DIFFERENT rows (R14/R15 bug).
__global__ __launch_bounds__(448, 1)
void gru_attn_fused(const float* __restrict__ x,
                    const float* __restrict__ w_ih0, const float* __restrict__ w_hh0,
                    const float* __restrict__ b_ih0, const float* __restrict__ b_hh0,
                    const float* __restrict__ w_ih1, const float* __restrict__ w_hh1,
                    const float* __restrict__ b_ih1, const float* __restrict__ b_hh1,
                    const float* __restrict__ attn_w1, const float* __restrict__ attn_b1,
                    const float* __restrict__ attn_w2, const float* __restrict__ attn_b2,
                    const float* __restrict__ ln_g, const float* __restrict__ ln_b,
                    const float* __restrict__ head_w1, const float* __restrict__ head_b1,
                    const float* __restrict__ head_w2, const float* __restrict__ head_b2,
                    float* __restrict__ out)
{
  __shared__ float lds[LDSF];
  f16*   ldsx = (f16*)lds;
  float* xg0  = lds + XG0_B;
  float* xg1  = lds + XG1_B;
  f16*   h0h  = (f16*)(lds + H0H_B);
  f16*   h1h  = (f16*)(lds + H1H_B);
  float* h1f  = lds + H1F_B;

  const int tid  = threadIdx.x;
  const int wid  = tid >> 6;
  const int lane = tid & 63;
  const int b    = blockIdx.x;
  const float* xb = x + (size_t)b * 64 * TS;

  const int i2     = lane >> 1;
  const int p      = lane & 1;
  const int ownrow = i2 + 32*p;
  const int hoff   = p << 5;

  f16x2 W[96];
  float4 SP[16];
  float bA=0.f,bB=0.f,bC=0.f,w2o=0.f,b2v=0.f;

  if (wid < 4) {
    const float* wsrc = (wid==0)? w_hh0 : (wid==1)? w_hh1 : (wid==2)? w_ih1 : w_ih0;
    for (int r2=0;r2<2;r2++)
      for (int g=0;g<3;g++)
        for (int m=0;m<16;m++){
          const f32x2 v = *(const f32x2*)(wsrc + (size_t)(g*64 + i2 + 32*r2)*64 + hoff + 2*m);
          W[(r2*3+g)*16+m] = (f16x2){(f16)v.x,(f16)v.y};
        }
    for (int q2=0;q2<96;q2++) asm volatile("" : "+v"(W[q2]));
    const float* bsrc = (wid==0)? b_hh0 : (wid==1)? b_hh1 : (wid==2)? b_ih1 : b_ih0;
    bA = bsrc[ownrow]; bB = bsrc[64+ownrow]; bC = bsrc[128+ownrow];
  } else if (wid == 6) {
    for (int r2=0;r2<2;r2++)
      for (int m=0;m<16;m++){
        const f32x2 v = *(const f32x2*)(attn_w1 + (size_t)(i2+32*r2)*64 + hoff + 2*m);
        W[r2*16+m] = (f16x2){(f16)v.x,(f16)v.y};
      }
    for (int q2=0;q2<32;q2++) asm volatile("" : "+v"(W[q2]));
    bA = attn_b1[ownrow]; w2o = attn_w2[ownrow]; b2v = attn_b2[0];
  }

  for (int idx = tid; idx < 1024; idx += 448) ((uint32_t*)h0h)[idx] = 0u;
  for (int idx = tid; idx < 512;  idx += 448) ((uint32_t*)h1h)[idx] = 0u;
  if (wid == 4) {
    const float* src = xb + (size_t)lane*TS;
    #pragma unroll
    for (int kq=0;kq<16;kq++) SP[kq] = *(const float4*)(src + 4*kq);
    #pragma unroll
    for (int kq=0;kq<16;kq++){
      ldsx[(4*kq+0)*80 + lane] = (f16)SP[kq].x;
      ldsx[(4*kq+1)*80 + lane] = (f16)SP[kq].y;
      ldsx[(4*kq+2)*80 + lane] = (f16)SP[kq].z;
      ldsx[(4*kq+3)*80 + lane] = (f16)SP[kq].w;
    }
  }
  __syncthreads();

  if (wid <= 1) __builtin_amdgcn_s_setprio(1);

  float hreg = 0.f;
  float am = -1e30f, aZ = 0.f, aP = 0.f;

  #pragma unroll 1
  for (int k = -1; k <= 258; ++k) {
    if (wid <= 1) {
      const int blk = k - (wid << 1);
      if (0 <= blk && blk < 256) {
        f16*   hring = wid ? h1h : h0h;
        float* xgc   = wid ? xg1 : xg0;
        const int emask = wid ? 1023 : 2047;
        // xg preamble read for step 8*blk (written a full SB ago; barrier-safe)
        const int t0 = blk << 3;
        float xgr = xgc[(t0&15)*192 + ownrow];
        float xgz = xgc[(t0&15)*192 + 64 + ownrow];
        float xgn = xgc[(t0&15)*192 + 128 + ownrow];
        #pragma unroll
        for (int j=0;j<8;j++){
          const int t = t0 + j;
          FEN();                                            // drain h write(t-1) + xg reads
          const f16* hv = hring + (((t-1)<<6) & emask) + hoff;
          float a00=0,a01=0,a02=0,a10=0,a11=0,a12=0;
          dot6(hv, W, a00,a01,a02,a10,a11,a12);
          a00=qadd1(a00); a01=qadd1(a01); a02=qadd1(a02);   // reduce EACH, then select
          a10=qadd1(a10); a11=qadd1(a11); a12=qadd1(a12);
          const float hr = p ? a10 : a00;
          const float hz = p ? a11 : a01;
          const float hn = p ? a12 : a02;
          const float r = sigmoidf_(xgr + hr + bA);
          const float z = sigmoidf_(xgz + hz + bB);
          const float n = tanhf_(xgn + r*(hn + bC));
          hreg = n + z*(hreg - n);
          hring[((t<<6) & emask) + ownrow] = (f16)hreg;
          if (wid) h1f[((t&15)<<6) + ownrow] = hreg;
          if (j < 7) {                                      // prefetch xg(t+1), same SB
            const int xi = ((t+1)&15)*192;
            xgr = xgc[xi + ownrow];
            xgz = xgc[xi + 64 + ownrow];
            xgn = xgc[xi + 128 + ownrow];
          }
        }
      }
    } else if (wid <= 3) {
      const int blk = (wid==2) ? k-1 : k+1;
      if (0 <= blk && blk < 256) {
        float* xgw = (wid==2) ? xg1 : xg0;
        #pragma unroll
        for (int j=0;j<8;j++){
          const int t = (blk<<3) + j;
          const f16* vec;
          if (wid==2) vec = h0h + (((t-1)<<6) & 2047) + hoff;
          else        vec = ldsx + ((t>>6)&1)*5120 + (t&63)*80 + hoff;
          float a00=0,a01=0,a02=0,a10=0,a11=0,a12=0;
          dot6(vec, W, a00,a01,a02,a10,a11,a12);
          a00=qadd1(a00); a01=qadd1(a01); a02=qadd1(a02);   // reduce EACH, then select
          a10=qadd1(a10); a11=qadd1(a11); a12=qadd1(a12);
          const int xi = (t & 15) * 192;
          xgw[xi + ownrow]       = (p ? a10 : a00) + bA;
          xgw[xi + 64 + ownrow]  = (p ? a11 : a01) + bB;
          xgw[xi + 128 + ownrow] = (p ? a12 : a02) + bC;
        }
      }
    } else if (wid == 4) {
      const int kk = k + 1, tile = kk >> 3, ph = kk & 7;
      if (ph == 1 && tile < 31) {
        const float* src = xb + (size_t)lane*TS + (tile+1)*64;
        #pragma unroll
        for (int kq=0;kq<16;kq++) SP[kq] = *(const float4*)(src + 4*kq);
      } else if (ph == 5 && tile < 31) {
        f16* dsth = ldsx + ((tile+1)&1)*5120;
        #pragma unroll
        for (int kq=0;kq<16;kq++){
          dsth[(4*kq+0)*80 + lane] = (f16)SP[kq].x;
          dsth[(4*kq+1)*80 + lane] = (f16)SP[kq].y;
          dsth[(4*kq+2)*80 + lane] = (f16)SP[kq].z;
          dsth[(4*kq+3)*80 + lane] = (f16)SP[kq].w;
        }
      }
    } else if (wid == 6) {
      const int blk = k - 3;
      if (0 <= blk && blk < 256) {
        #pragma unroll
        for (int j=0;j<8;j++){
          const int t = (blk<<3) + j;
          const f16* hv = h1h + ((t&15)<<6) + hoff;
          H8 u[4];
          u[0].v8 = *(const f16x8*)(hv);
          u[1].v8 = *(const f16x8*)(hv+8);
          u[2].v8 = *(const f16x8*)(hv+16);
          u[3].v8 = *(const f16x8*)(hv+24);
          float a0=0.f, a1=0.f;
          #pragma unroll
          for (int m=0;m<16;m++){
            const f16x2 hm = u[m>>2].v2[m&3];
            a0 = fdot2_(W[m],    hm, a0);
            a1 = fdot2_(W[16+m], hm, a1);
          }
          a0 = qadd1(a0); a1 = qadd1(a1);                   // reduce EACH, then select
          const float a  = tanhf_((p ? a1 : a0) + bA);
          const float s  = wsum64(w2o * a) + b2v;
          const float hc = h1f[((t&15)<<6) + lane];
          const float mn = fmaxf(am, s);
          const float sc = __expf(am - mn);
          const float pp = __expf(s - mn);
          aZ = aZ*sc + pp;
          aP = aP*sc + pp*hc;
          am = mn;
        }
      }
    }
    BAR();
  }

  // ---------------- epilogue ----------------
  if (wid == 6) {
    const float pooled = aP / aZ;
    float mu = pooled;
    #pragma unroll
    for (int m=1;m<64;m<<=1) mu += __shfl_xor(mu, m, 64);
    mu *= (1.0f/64.0f);
    const float d = pooled - mu;
    float var = d*d;
    #pragma unroll
    for (int m=1;m<64;m<<=1) var += __shfl_xor(var, m, 64);
    var *= (1.0f/64.0f);
    const float y = d * rsqrtf(var + 1e-5f) * ln_g[lane] + ln_b[lane];
    lds[SCRO_B + lane] = y;
  }
  __syncthreads();
  if (tid < 32) {
    const float* hw = head_w1 + tid*64;
    float acc = head_b1[tid];
    #pragma unroll
    for (int kq=0;kq<16;kq++){
      const float4 w4 = ((const float4*)hw)[kq];
      acc += w4.x*lds[SCRO_B+4*kq+0] + w4.y*lds[SCRO_B+4*kq+1]
           + w4.z*lds[SCRO_B+4*kq+2] + w4.w*lds[SCRO_B+4*kq+3];
    }
    const float u = 0.5f*acc*(1.0f + erff(acc*0.70710678118654752f)); // exact GELU
    lds[SCRO_B + 64 + tid] = u;
  }
  __syncthreads();
  if (tid < 8) {
    const float* hw = head_w2 + tid*32;
    float acc = head_b2[tid];
    #pragma unroll
    for (int kq=0;kq<8;kq++){
      const float4 w4 = ((const float4*)hw)[kq];
      acc += w4.x*lds[SCRO_B+64+4*kq+0] + w4.y*lds[SCRO_B+64+4*kq+1]
           + w4.z*lds[SCRO_B+64+4*kq+2] + w4.w*lds[SCRO_B+64+4*kq+3];
    }
    out[b*8 + tid] = acc;
  }
}

extern "C" void kernel_launch(void* const* d_in, const int* in_sizes, int n_in,
                              void* d_out, int out_size, void* d_ws, size_t ws_size,
                              hipStream_t stream) {
  (void)in_sizes; (void)n_in; (void)d_ws; (void)ws_size; (void)out_size;
  const float* x       = (const float*)d_in[0];
  const float* w_ih0   = (const float*)d_in[1];
  const float* w_hh0   = (const float*)d_in[2];
  const float* b_ih0   = (const float*)d_in[3];
  const float* b_hh0   = (const float*)d_in[4];
  const float* w_ih1   = (const float*)d_in[5];
  const float* w_hh1   = (const float*)d_in[6];
  const float* b_ih1   = (const float*)d_in[7];
  const float* b_hh1   = (const float*)d_in[8];
  const float* attn_w1 = (const float*)d_in[9];
  const float* attn_b1 = (const float*)d_in[10];
  const float* attn_w2 = (const float*)d_in[11];
  const float* attn_b2 = (const float*)d_in[12];
  const float* ln_g    = (const float*)d_in[13];
  const float* ln_b    = (const float*)d_in[14];
  const float* head_w1 = (const float*)d_in[15];
  const float* head_b1 = (const float*)d_in[16];
  const float* head_w2 = (const float*)d_in[17];
  const float* head_b2 = (const float*)d_in[18];
  hipLaunchKernelGGL(gru_attn_fused, dim3(256), dim3(448), 0, stream,
                     x, w_ih0, w_hh0, b_ih0, b_hh0, w_ih1, w_hh1, b_ih1, b_hh1,
                     attn_w1, attn_b1, attn_w2, attn_b2, ln_g, ln_b,
                     head_w1, head_b1, head_w2, head_b2, (float*)d_out);
}